// Round 5
// baseline (69.358 us; speedup 1.0000x reference)
//
#include <hip/hip_runtime.h>
#include <stdint.h>

#define DD 512
#define NP 1024
#define NB 16

typedef __attribute__((ext_vector_type(8))) __bf16 bf16x8;
typedef __attribute__((ext_vector_type(4))) float f32x4;

// ws layout (floats):
//   qhw  : 2 halves x [16384][64]      at 0        (8 MB)
//   khw  : 2 halves x [16][64][1024]   at 2097152  (8 MB)
//   tbl  : bf16 [2][64][256] swizzled  at 4194304  (64 KB)
//   G    : f32 [64][64]                after tbl   (16 KB)
#define QHW_HALF 1048576
#define KHW_HALF 1048576

__device__ __forceinline__ bf16x8 cvt8(const float4& a, const float4& b) {
    bf16x8 r;
    r[0]=(__bf16)a.x; r[1]=(__bf16)a.y; r[2]=(__bf16)a.z; r[3]=(__bf16)a.w;
    r[4]=(__bf16)b.x; r[5]=(__bf16)b.y; r[6]=(__bf16)b.z; r[7]=(__bf16)b.w;
    return r;
}

// EHW row r: r<32 -> embed[r*32][col..]; r>=32 -> embed[r-32][col..] - embed[0][col..]
__device__ __forceinline__ bf16x8 ehw_row(const float* __restrict__ embed, int r,
                                          int col, const float4& z0, const float4& z1) {
    int srcrow = (r < 32) ? (r << 5) : (r - 32);
    const float* sp = embed + (size_t)srcrow * DD + col;
    float4 a = *(const float4*)sp;
    float4 b = *(const float4*)(sp + 4);
    if (r >= 32) {
        a.x -= z0.x; a.y -= z0.y; a.z -= z0.z; a.w -= z0.w;
        b.x -= z1.x; b.y -= z1.y; b.z -= z1.z; b.w -= z1.w;
    }
    return cvt8(a, b);
}

// ---------- prep: blocks 0..15 build pre-swizzled bf16 table; block 16 builds G ----------
__global__ __launch_bounds__(256) void prep(
    const float* __restrict__ embed, unsigned short* __restrict__ tbl,
    float* __restrict__ G)
{
    const int tid = threadIdx.x;
    if (blockIdx.x < 16) {
        int g = blockIdx.x * 256 + tid;        // 0..4095
        int row = g >> 6;                      // 0..63
        int c8  = (g & 63) * 8;                // 0..504
        float4 z0 = *(const float4*)(embed + c8);
        float4 z1 = *(const float4*)(embed + c8 + 4);
        bf16x8 r = ehw_row(embed, row, c8, z0, z1);
        int h  = c8 >> 8;
        int cl = c8 & 255;
        int byte = (cl * 2) ^ ((row & 7) << 4);          // bake the LDS swizzle
        *(bf16x8*)((char*)tbl + h * 32768 + row * 512 + byte) = r;
    } else {
        // G = EHW . EHW^T  (64x64), 4 waves x (16 rows x 64 cols)
        const int lane = tid & 63, wid = tid >> 6;
        const int lr = lane & 15, kq = (lane >> 4) * 8;
        f32x4 acc[4];
        #pragma unroll
        for (int n = 0; n < 4; ++n) acc[n] = (f32x4)0.0f;
        for (int ks = 0; ks < 16; ++ks) {
            int col = ks * 32 + kq;
            float4 z0 = *(const float4*)(embed + col);
            float4 z1 = *(const float4*)(embed + col + 4);
            bf16x8 af = ehw_row(embed, wid * 16 + lr, col, z0, z1);
            #pragma unroll
            for (int n = 0; n < 4; ++n) {
                bf16x8 bf = ehw_row(embed, n * 16 + lr, col, z0, z1);
                acc[n] = __builtin_amdgcn_mfma_f32_16x16x32_bf16(af, bf, acc[n], 0, 0, 0);
            }
        }
        int row0 = wid * 16 + (lane >> 4) * 4;
        #pragma unroll
        for (int n = 0; n < 4; ++n)
            #pragma unroll
            for (int i = 0; i < 4; ++i)
                G[(size_t)(row0 + i) * 64 + n * 16 + lr] = acc[n][i];
    }
}

// ---------- rank gemm: pure stream vs LDS table, split-K ----------
// bid: gsel = bid>>9 (0: stream q -> qhw, 1: stream k -> khw)
//      khalf = (bid>>8)&1, tile = bid&255 (64 streamed rows each)
__device__ __forceinline__ void gload_lds16(const void* g, void* l) {
    __builtin_amdgcn_global_load_lds(
        (const __attribute__((address_space(1))) unsigned int*)g,
        (__attribute__((address_space(3))) unsigned int*)l,
        16, 0, 0);
}

__global__ __launch_bounds__(256) void rank_gemm(
    const float* __restrict__ q, const float* __restrict__ kin,
    const unsigned short* __restrict__ tbl,
    float* __restrict__ qhw, float* __restrict__ khw)
{
    __shared__ __align__(16) unsigned short T[64 * 256];   // 32 KB swizzled

    const int tid  = threadIdx.x;
    const int lane = tid & 63;
    const int wid  = tid >> 6;
    const int gsel  = blockIdx.x >> 9;
    const int khalf = (blockIdx.x >> 8) & 1;
    const int tile  = blockIdx.x & 255;
    const int lr = lane & 15;
    const int kq = (lane >> 4) * 8;

    // stage 32KB table half (pre-swizzled in global -> linear DMA)
    const char* src = (const char*)tbl + khalf * 32768;
    #pragma unroll
    for (int c = 0; c < 8; ++c) {
        int off = wid * 8192 + c * 1024;
        gload_lds16(src + off + lane * 16, (char*)T + off);
    }

    const int grow = tile * 64 + wid * 16 + lr;       // streamed row (global)
    const float* srcA = (gsel ? kin : q) + (size_t)grow * DD + khalf * 256 + kq;

    f32x4 acc[4];
    #pragma unroll
    for (int n = 0; n < 4; ++n) acc[n] = (f32x4)0.0f;

    __syncthreads();

    #pragma unroll 4
    for (int ks = 0; ks < 8; ++ks) {
        float4 a0 = *(const float4*)(srcA + ks * 32);
        float4 a1 = *(const float4*)(srcA + ks * 32 + 4);
        bf16x8 sf = cvt8(a0, a1);
        bf16x8 ef[4];
        #pragma unroll
        for (int n = 0; n < 4; ++n) {
            int row = n * 16 + lr;
            int byte = ((ks * 32 + kq) * 2) ^ ((row & 7) << 4);
            ef[n] = *(const bf16x8*)((const char*)T + row * 512 + byte);
        }
        if (!gsel) {
            #pragma unroll
            for (int n = 0; n < 4; ++n)
                acc[n] = __builtin_amdgcn_mfma_f32_16x16x32_bf16(sf, ef[n], acc[n], 0, 0, 0);
        } else {
            #pragma unroll
            for (int n = 0; n < 4; ++n)
                acc[n] = __builtin_amdgcn_mfma_f32_16x16x32_bf16(ef[n], sf, acc[n], 0, 0, 0);
        }
    }

    if (!gsel) {
        // C row -> streamed P, C col -> table m
        float* o = qhw + (size_t)khalf * QHW_HALF
                 + (size_t)(tile * 64 + wid * 16 + (lane >> 4) * 4) * 64 + lr;
        #pragma unroll
        for (int n = 0; n < 4; ++n)
            #pragma unroll
            for (int i = 0; i < 4; ++i)
                o[(size_t)i * 64 + n * 16] = acc[n][i];
    } else {
        // C row -> table m, C col -> streamed Q
        int b = grow >> 10, Q = grow & 1023;
        float* o = khw + (size_t)khalf * KHW_HALF + (size_t)b * 65536 + Q;
        int m0 = (lane >> 4) * 4;
        #pragma unroll
        for (int n = 0; n < 4; ++n)
            #pragma unroll
            for (int i = 0; i < 4; ++i)
                o[(size_t)(n * 16 + m0 + i) * 1024] = acc[n][i];
    }
}

// ---------- assemble: out = khA+khB + kwA+kwB + d1[j][kq] + d2[j][lq] ----------
// d1[j][kq] = qhw[P][kq] + G[i][kq] + G[32+j][kq]
// d2[j][lq] = qhw[P][32+lq] + G[i][32+lq] + G[32+j][32+lq]
__global__ __launch_bounds__(256) void assemble(
    const float* __restrict__ qhw, const float* __restrict__ khw,
    const float* __restrict__ G, float* __restrict__ out)
{
    __shared__ __align__(16) float kh[NP];
    __shared__ __align__(16) float d1[16][32];
    __shared__ __align__(16) float d2[16][32];

    const int tid = threadIdx.x;
    const int b   = blockIdx.x >> 6;
    const int i   = (blockIdx.x >> 1) & 31;
    const int jh  = blockIdx.x & 1;

    const float* khA = khw + (size_t)b * 65536 + (size_t)i * 1024;
    const float* khB = khA + KHW_HALF;
    float4 ka = ((const float4*)khA)[tid];
    float4 kb = ((const float4*)khB)[tid];
    float4 ks; ks.x = ka.x + kb.x; ks.y = ka.y + kb.y; ks.z = ka.z + kb.z; ks.w = ka.w + kb.w;
    ((float4*)kh)[tid] = ks;

    {
        int jj = tid >> 4, c = tid & 15;
        int j  = jh * 16 + jj;
        size_t Prow = (size_t)b * NP + i * 32 + j;
        const float* qA = qhw + Prow * 64;
        const float* qB = qA + QHW_HALF;
        const float* Gi = G + (size_t)i * 64;
        const float* Gj = G + (size_t)(32 + j) * 64;
        d1[jj][c]      = qA[c]      + qB[c]      + Gi[c]      + Gj[c];
        d1[jj][c + 16] = qA[c + 16] + qB[c + 16] + Gi[c + 16] + Gj[c + 16];
        d2[jj][c]      = qA[32 + c]      + qB[32 + c]      + Gi[32 + c]      + Gj[32 + c];
        d2[jj][c + 16] = qA[48 + c] + qB[48 + c] + Gi[48 + c] + Gj[48 + c];
    }
    __syncthreads();

    const int Q0 = tid * 4;
    const int kidx = Q0 >> 5;
    const int lidx = Q0 & 31;
    const float4 khv = *(const float4*)&kh[Q0];

    float* orow = out + ((size_t)b * NP + i * 32 + jh * 16) * NP + Q0;
    const float* kwA = khw + (size_t)b * 65536 + (size_t)(32 + jh * 16) * 1024 + Q0;
    const float* kwB = kwA + KHW_HALF;

    #pragma unroll 4
    for (int jj = 0; jj < 16; ++jj) {
        float4 ka2 = *(const float4*)(kwA + (size_t)jj * 1024);
        float4 kb2 = *(const float4*)(kwB + (size_t)jj * 1024);
        float  s1  = d1[jj][kidx];
        float4 s2  = *(const float4*)&d2[jj][lidx];
        float4 v;
        v.x = khv.x + ka2.x + kb2.x + s1 + s2.x;
        v.y = khv.y + ka2.y + kb2.y + s1 + s2.y;
        v.z = khv.z + ka2.z + kb2.z + s1 + s2.z;
        v.w = khv.w + ka2.w + kb2.w + s1 + s2.w;
        *(float4*)(orow + (size_t)jj * NP) = v;
    }
}

extern "C" void kernel_launch(void* const* d_in, const int* in_sizes, int n_in,
                              void* d_out, int out_size, void* d_ws, size_t ws_size,
                              hipStream_t stream) {
    const float* q = (const float*)d_in[0];
    const float* k = (const float*)d_in[1];
    const float* e = (const float*)d_in[2];
    float* out = (float*)d_out;

    float* qhw = (float*)d_ws;
    float* khw = qhw + 2 * (size_t)QHW_HALF;
    unsigned short* tbl = (unsigned short*)(khw + 2 * (size_t)KHW_HALF);
    float* G = (float*)((char*)tbl + 65536);

    hipLaunchKernelGGL(prep, dim3(17), dim3(256), 0, stream, e, tbl, G);
    hipLaunchKernelGGL(rank_gemm, dim3(1024), dim3(256), 0, stream, q, k, tbl, qhw, khw);
    hipLaunchKernelGGL(assemble, dim3(1024), dim3(256), 0, stream, qhw, khw, G, out);
}